// Round 7
// baseline (282.996 us; speedup 1.0000x reference)
//
#include <hip/hip_runtime.h>
#include <hip/hip_cooperative_groups.h>
#include <math.h>

namespace cg = cooperative_groups;

// Problem constants (x: [8192, 512] fp32, K=5, eps=1e-8, scalar fp32 loss)
#define NROWS 8192
#define DIM   512
#define KNN   5
#define EPSV  1e-8f

// GEMM tiling: 128x128 tile, BK=32, 4 waves (2x2), each wave 4x4 of 16x16x32 MFMA
#define BM 128
#define BN 128
#define BK 32
#define NT 64                  // 64 tile indices per dimension
#define NTILES 2080            // upper-triangular incl. diagonal: 64*65/2
#define NT64 (NROWS / 64)      // 128 64-col tiles per row
#define MAXGRID 1024

typedef __attribute__((ext_vector_type(8))) _Float16 f16x8;
typedef __attribute__((ext_vector_type(4))) float    f32x4;

// async global->LDS, 16B per lane (LDS dest must be wave-uniform base + lane*16)
__device__ __forceinline__ void gload16(const _Float16* g, _Float16* l) {
    __builtin_amdgcn_global_load_lds(
        (const __attribute__((address_space(1))) void*)g,
        (__attribute__((address_space(3))) void*)l, 16, 0, 0);
}

__device__ __forceinline__ void cmpswap(float& a, float& b) {
    const float hi = fmaxf(a, b), lo = fminf(a, b);
    a = hi; b = lo;
}

// merge two sorted-descending 5-lists -> top-5 (into a).
__device__ __forceinline__ void merge5(float a[KNN], const float b[KNN]) {
    const float c0 = fmaxf(a[0], b[0]);
    const float c1 = fmaxf(fmaxf(a[1], b[1]), fminf(a[0], b[0]));
    const float c2 = fmaxf(fmaxf(a[2], b[2]),
                           fmaxf(fminf(a[0], b[1]), fminf(a[1], b[0])));
    const float c3 = fmaxf(fmaxf(a[3], b[3]),
                           fmaxf(fminf(a[0], b[2]),
                                 fmaxf(fminf(a[1], b[1]), fminf(a[2], b[0]))));
    const float c4 = fmaxf(fmaxf(a[4], b[4]),
                           fmaxf(fmaxf(fminf(a[0], b[3]), fminf(a[1], b[2])),
                                 fmaxf(fminf(a[2], b[1]), fminf(a[3], b[0]))));
    a[0] = c0; a[1] = c1; a[2] = c2; a[3] = c3; a[4] = c4;
}

// ===========================================================================
// Device helpers shared by fused + fallback paths
// ===========================================================================
__device__ __forceinline__ void normalize_row(const float* __restrict__ x,
                                              _Float16* __restrict__ xnh,
                                              int row, int lane) {
    const float4* xr = (const float4*)(x + (size_t)row * DIM) + lane * 2;
    const float4 a = xr[0];
    const float4 b = xr[1];
    float s = a.x * a.x + a.y * a.y + a.z * a.z + a.w * a.w
            + b.x * b.x + b.y * b.y + b.z * b.z + b.w * b.w;
    #pragma unroll
    for (int off = 1; off < 64; off <<= 1) s += __shfl_xor(s, off, 64);
    const float inv = 1.0f / sqrtf(s);
    const f16x8 h = { (_Float16)(a.x * inv), (_Float16)(a.y * inv),
                      (_Float16)(a.z * inv), (_Float16)(a.w * inv),
                      (_Float16)(b.x * inv), (_Float16)(b.y * inv),
                      (_Float16)(b.z * inv), (_Float16)(b.w * inv) };
    *(f16x8*)(xnh + (size_t)row * DIM + lane * 8) = h;
}

// exact per-row top-5 from 128 stored triples (+ rare exact recompute);
// returns log(mean_rho + eps) for this row. Wave-wide.
__device__ __forceinline__ float row_loss(const _Float16* __restrict__ xnh,
                                          const float* __restrict__ M3,
                                          int row, int lane) {
    const float* p = M3 + (size_t)row * NT64 * 3 + lane * 6;
    float a[3], b[3];
    a[0] = p[0]; a[1] = p[1]; a[2] = p[2];
    b[0] = p[3]; b[1] = p[4]; b[2] = p[5];

    float t[KNN];
    {
        float c[KNN] = { a[0], a[1], a[2], -2.f, -2.f };
        const float bb[KNN] = { b[0], b[1], b[2], -2.f, -2.f };
        merge5(c, bb);
        #pragma unroll
        for (int d = 1; d < 64; d <<= 1) {
            float o[KNN];
            #pragma unroll
            for (int k = 0; k < KNN; ++k) o[k] = __shfl_xor(c[k], d, 64);
            merge5(c, o);
        }
        #pragma unroll
        for (int k = 0; k < KNN; ++k) t[k] = c[k];
    }

    const unsigned long long ba  = __ballot(a[2] >= t[4]);
    const unsigned long long bb_ = __ballot(b[2] >= t[4]);
    if (ba | bb_) {
        const bool fA = (ba >> lane) & 1ull, fB = (bb_ >> lane) & 1ull;
        float c[KNN] = { fA ? -2.f : a[0], fA ? -2.f : a[1],
                         fA ? -2.f : a[2], -2.f, -2.f };
        const float b5[KNN] = { fB ? -2.f : b[0], fB ? -2.f : b[1],
                                fB ? -2.f : b[2], -2.f, -2.f };
        merge5(c, b5);
        #pragma unroll
        for (int d = 1; d < 64; d <<= 1) {
            float o[KNN];
            #pragma unroll
            for (int k = 0; k < KNN; ++k) o[k] = __shfl_xor(c[k], d, 64);
            merge5(c, o);
        }
        #pragma unroll
        for (int k = 0; k < KNN; ++k) t[k] = c[k];

        unsigned long long fl[2] = { ba, bb_ };
        #pragma unroll
        for (int h = 0; h < 2; ++h) {
            unsigned long long mm = fl[h];
            while (mm) {
                const int l = __ffsll((long long)mm) - 1;
                mm &= mm - 1;
                const int col = (2 * l + h) * 64 + lane;
                const _Float16* rp = xnh + (size_t)row * DIM;
                const _Float16* cp = xnh + (size_t)col * DIM;
                float d = 0.f;
                for (int k8 = 0; k8 < DIM / 8; ++k8) {
                    const f16x8 rv = *(const f16x8*)(rp + k8 * 8);
                    const f16x8 cv = *(const f16x8*)(cp + k8 * 8);
                    #pragma unroll
                    for (int e = 0; e < 8; ++e)
                        d += (float)rv[e] * (float)cv[e];
                }
                if (col == row) d = -2.f;
                float c2[KNN] = { d, -2.f, -2.f, -2.f, -2.f };
                #pragma unroll
                for (int dd = 1; dd < 64; dd <<= 1) {
                    float o[KNN];
                    #pragma unroll
                    for (int k = 0; k < KNN; ++k) o[k] = __shfl_xor(c2[k], dd, 64);
                    merge5(c2, o);
                }
                merge5(t, c2);
            }
        }
    }

    float s = 0.f;
    #pragma unroll
    for (int k = 0; k < KNN; ++k) s += sqrtf(fmaxf(2.f - 2.f * t[k], 0.f));
    return logf(s * (1.f / KNN) + EPSV);
}

// one triangular Gram tile: GEMM + row-side/col-side top-3 harvest into M3
__device__ __forceinline__ void do_tile(const _Float16* __restrict__ xnh,
                                        float* __restrict__ M3,
                                        _Float16* As, _Float16* Bs,
                                        int I, int J, int tid) {
    const int lane   = tid & 63;
    const int wv     = tid >> 6;
    const int wm     = wv >> 1;
    const int wn     = wv & 1;
    const int m_lane = lane & 15;
    const int quad   = lane >> 4;

    const int i0 = I * BM;
    const int j0 = J * BN;
    const int rowlocal = (m_lane >> 2) * 16 + quad * 4 + (m_lane & 3);
    const int myrow    = i0 + wm * 64 + rowlocal;

    f32x4 acc[4][4];
    #pragma unroll
    for (int m = 0; m < 4; ++m)
        #pragma unroll
        for (int n = 0; n < 4; ++n)
            acc[m][n] = (f32x4){0.f, 0.f, 0.f, 0.f};

    for (int ks = 0; ks < DIM / BK; ++ks) {
        const int k0 = ks * BK;
        #pragma unroll
        for (int q = 0; q < 2; ++q) {
            const int s  = tid + q * 256;
            const int r  = s >> 2;
            const int kk = s & 3;
            gload16(xnh + (size_t)(i0 + r) * DIM + k0 + kk * 8, As + s * 8);
            gload16(xnh + (size_t)(j0 + r) * DIM + k0 + kk * 8, Bs + s * 8);
        }
        __syncthreads();

        f16x8 af[4], bf[4];
        #pragma unroll
        for (int m = 0; m < 4; ++m)
            af[m] = *(const f16x8*)(As + (wm * 64 + m * 16 + m_lane) * BK + quad * 8);
        #pragma unroll
        for (int n = 0; n < 4; ++n)
            bf[n] = *(const f16x8*)(Bs + (wn * 64 + n * 16 + m_lane) * BK + quad * 8);
        #pragma unroll
        for (int m = 0; m < 4; ++m)
            #pragma unroll
            for (int n = 0; n < 4; ++n)
                acc[m][n] = __builtin_amdgcn_mfma_f32_16x16x32_f16(af[m], bf[n], acc[m][n], 0, 0, 0);
        __syncthreads();
    }

    const bool diag = (I == J) && (wm == wn);
    #pragma unroll
    for (int m = 0; m < 4; ++m)
        #pragma unroll
        for (int i = 0; i < 4; ++i)
            acc[m][m][i] = (diag && (quad * 4 + i) == m_lane) ? -2.f : acc[m][m][i];

    // row-side: per (m,i), top-3 of this row's 64 cols (butterfly)
    float g1 = -2.f, g2 = -2.f, g3 = -2.f;
    #pragma unroll
    for (int m = 0; m < 4; ++m) {
        #pragma unroll
        for (int i = 0; i < 4; ++i) {
            float v0 = acc[m][0][i], v1 = acc[m][1][i];
            float v2 = acc[m][2][i], v3 = acc[m][3][i];
            cmpswap(v0, v1); cmpswap(v2, v3);
            cmpswap(v0, v2); cmpswap(v1, v3);
            cmpswap(v1, v2);
            float a1 = v0, a2 = v1, a3 = v2;
            #pragma unroll
            for (int d = 1; d < 16; d <<= 1) {
                const float b1 = __shfl_xor(a1, d, 64);
                const float b2 = __shfl_xor(a2, d, 64);
                const float b3 = __shfl_xor(a3, d, 64);
                const float n1 = fmaxf(a1, b1);
                const float n2 = fmaxf(fminf(a1, b1), fmaxf(a2, b2));
                const float n3 = fmaxf(fmaxf(a3, b3),
                                       fmaxf(fminf(a1, b2), fminf(a2, b1)));
                a1 = n1; a2 = n2; a3 = n3;
            }
            const bool own = (m_lane == m * 4 + i);
            g1 = own ? a1 : g1; g2 = own ? a2 : g2; g3 = own ? a3 : g3;
        }
    }
    {
        float* p = M3 + ((size_t)myrow * NT64 + (J * 2 + wn)) * 3;
        p[0] = g1; p[1] = g2; p[2] = g3;
    }

    // col-side (I != J): per n, top-3 of this col's 64 rows
    if (I != J) {
        #pragma unroll
        for (int n = 0; n < 4; ++n) {
            float c1 = -2.f, c2 = -2.f, c3 = -2.f;
            #pragma unroll
            for (int m = 0; m < 4; ++m)
                #pragma unroll
                for (int i = 0; i < 4; ++i) {
                    const float v  = acc[m][n][i];
                    const float u1 = fminf(c1, v);
                    c1 = fmaxf(c1, v);
                    const float u2 = fminf(c2, u1);
                    c2 = fmaxf(c2, u1);
                    c3 = fmaxf(c3, u2);
                }
            #pragma unroll
            for (int d = 16; d < 64; d <<= 1) {
                const float b1 = __shfl_xor(c1, d, 64);
                const float b2 = __shfl_xor(c2, d, 64);
                const float b3 = __shfl_xor(c3, d, 64);
                const float n2 = fmaxf(fminf(c1, b1), fmaxf(c2, b2));
                const float n3 = fmaxf(fmaxf(c3, b3),
                                       fmaxf(fminf(c1, b2), fminf(c2, b1)));
                c1 = fmaxf(c1, b1); c2 = n2; c3 = n3;
            }
            if (quad == 0) {
                const int col = j0 + wn * 64 + n * 16 + m_lane;
                float* p = M3 + ((size_t)col * NT64 + (I * 2 + wm)) * 3;
                p[0] = c1; p[1] = c2; p[2] = c3;
            }
        }
    }
}

// ===========================================================================
// Fused cooperative kernel: grid-stride phases + dynamic tile queue.
// launch_bounds(256,2): <=256 regs/wave (fused body needs ~180 incl. AGPRs) —
// round-6 failed because (256,4) demanded co-residency the RF can't hold.
// ===========================================================================
__global__ __launch_bounds__(256, 2)
void fused_kernel(const float* __restrict__ x, _Float16* __restrict__ xnh,
                  float* __restrict__ M3, unsigned* __restrict__ cnt,
                  float* __restrict__ out) {
    cg::grid_group grid = cg::this_grid();

    __shared__ __align__(16) _Float16 As[BM * BK];   // 8 KB
    __shared__ __align__(16) _Float16 Bs[BN * BK];   // 8 KB
    __shared__ unsigned tsh;
    __shared__ float red[4];

    const int tid  = threadIdx.x;
    const int lane = tid & 63;
    const int wv   = tid >> 6;
    const int gw   = blockIdx.x * 4 + wv;     // global wave id
    const int nw   = gridDim.x * 4;           // total waves

    // ---------------- phase 1: row-normalize (grid-stride by wave) ----------
    for (int row = gw; row < NROWS; row += nw)
        normalize_row(x, xnh, row, lane);
    if (blockIdx.x == 0 && tid == 0) { *out = 0.f; *cnt = 0u; }
    grid.sync();

    // ---------------- phase 2: dynamic triangular tile queue ----------------
    for (;;) {
        if (tid == 0) tsh = atomicAdd(cnt, 1u);
        __syncthreads();
        const unsigned t = tsh;              // block-uniform
        if (t >= NTILES) break;              // uniform exit

        // map t -> (I,J), upper triangle row-major: base(I) = I*(129-I)/2
        int I = (int)((129.0 - sqrt(16641.0 - 8.0 * (double)t)) * 0.5);
        while ((I + 1) * (128 - I) / 2 <= (int)t) ++I;
        while (I * (129 - I) / 2 > (int)t) --I;
        const int J = I + ((int)t - I * (129 - I) / 2);

        do_tile(xnh, M3, As, Bs, I, J, tid);
        // As/Bs reuse next iteration is safe: last ks step ends in __syncthreads,
        // and the queue-grab barrier precedes the next gload16 batch.
    }
    grid.sync();

    // ---------------- phase 3: exact top-5 + loss (grid-stride by wave) -----
    float val = 0.f;
    for (int row = gw; row < NROWS; row += nw)
        val += row_loss(xnh, M3, row, lane);

    if (lane == 0) red[wv] = val;
    __syncthreads();
    if (tid == 0) {
        const float blocksum = red[0] + red[1] + red[2] + red[3];
        atomicAdd(out, -blocksum / (float)NROWS);
    }
}

// ===========================================================================
// Fallback path (round-5 proven): three plain kernels.
// ===========================================================================
__global__ __launch_bounds__(256) void norm_kernel(const float* __restrict__ x,
                                                   _Float16* __restrict__ xnh,
                                                   float* __restrict__ out) {
    const int wv = threadIdx.x >> 6, lane = threadIdx.x & 63;
    normalize_row(x, xnh, blockIdx.x * 4 + wv, lane);
    if (blockIdx.x == 0 && threadIdx.x == 0) *out = 0.f;
}

__global__ __launch_bounds__(256) void dots_top3_kernel(const _Float16* __restrict__ xnh,
                                                        float* __restrict__ M3) {
    const int I = blockIdx.x >> 6;
    const int J = blockIdx.x & 63;
    if (J < I) return;
    __shared__ __align__(16) _Float16 As[BM * BK];
    __shared__ __align__(16) _Float16 Bs[BN * BK];
    do_tile(xnh, M3, As, Bs, I, J, threadIdx.x);
}

__global__ __launch_bounds__(256) void select_loss_kernel(const _Float16* __restrict__ xnh,
                                                          const float* __restrict__ M3,
                                                          float* __restrict__ out) {
    const int wv = threadIdx.x >> 6, lane = threadIdx.x & 63;
    const float val = row_loss(xnh, M3, blockIdx.x * 4 + wv, lane);
    __shared__ float red[4];
    if (lane == 0) red[wv] = val;
    __syncthreads();
    if (threadIdx.x == 0) {
        const float blocksum = red[0] + red[1] + red[2] + red[3];
        atomicAdd(out, -blocksum / (float)NROWS);
    }
}

// ---------------------------------------------------------------------------
extern "C" void kernel_launch(void* const* d_in, const int* in_sizes, int n_in,
                              void* d_out, int out_size, void* d_ws, size_t ws_size,
                              hipStream_t stream) {
    const float* x = (const float*)d_in[0];
    float* out = (float*)d_out;
    char* ws = (char*)d_ws;

    _Float16* xnh = (_Float16*)ws;                                     // 8 MB
    float* M3 = (float*)(ws + (size_t)NROWS * DIM * sizeof(_Float16)); // 12.6 MB
    unsigned* cnt = (unsigned*)(ws + (size_t)NROWS * DIM * sizeof(_Float16)
                                + (size_t)NROWS * NT64 * 3 * sizeof(float));

    // runtime-verified co-residency: never request more blocks than fit
    int maxB = 0;
    hipError_t qerr = hipOccupancyMaxActiveBlocksPerMultiprocessor(
        &maxB, fused_kernel, 256, 0);
    int grid = (qerr == hipSuccess) ? maxB * 256 : 0;
    if (grid > MAXGRID) grid = MAXGRID;

    hipError_t lerr = hipErrorUnknown;
    if (grid >= 256) {   // need a sane amount of parallelism for one-shot
        void* args[] = { (void*)&x, (void*)&xnh, (void*)&M3, (void*)&cnt, (void*)&out };
        lerr = hipLaunchCooperativeKernel((const void*)fused_kernel, dim3(grid),
                                          dim3(256), args, 0, stream);
    }
    if (lerr != hipSuccess) {
        // deterministic fallback: proven 3-kernel pipeline
        norm_kernel<<<NROWS / 4, 256, 0, stream>>>(x, xnh, out);
        dots_top3_kernel<<<NT * NT, 256, 0, stream>>>(xnh, M3);
        select_loss_kernel<<<NROWS / 4, 256, 0, stream>>>(xnh, M3, out);
    }
}

// Round 8
// 188.806 us; speedup vs baseline: 1.4989x; 1.4989x over previous
//
#include <hip/hip_runtime.h>
#include <math.h>

// Problem constants (x: [8192, 512] fp32, K=5, eps=1e-8, scalar fp32 loss)
#define NROWS 8192
#define DIM   512
#define KNN   5
#define EPSV  1e-8f

// GEMM tiling: 128x128 tile, BK=64 (8 barrier-pairs/tile), 4 waves (2x2),
// each wave 4x4 of 16x16x32 MFMA, 2 k-chunks per staged step.
#define BM 128
#define BN 128
#define BK 64
#define NT 64                  // 64 tile indices per dimension
#define NTILES 2080            // upper triangle incl. diagonal: 64*65/2
#define NT64 (NROWS / 64)      // 128 64-col tiles per row

typedef __attribute__((ext_vector_type(8))) _Float16 f16x8;
typedef __attribute__((ext_vector_type(4))) float    f32x4;

// async global->LDS, 16B per lane (LDS dest must be wave-uniform base + lane*16)
__device__ __forceinline__ void gload16(const _Float16* g, _Float16* l) {
    __builtin_amdgcn_global_load_lds(
        (const __attribute__((address_space(1))) void*)g,
        (__attribute__((address_space(3))) void*)l, 16, 0, 0);
}

__device__ __forceinline__ void cmpswap(float& a, float& b) {
    const float hi = fmaxf(a, b), lo = fminf(a, b);
    a = hi; b = lo;
}

// merge two sorted-descending 5-lists -> top-5 (into a).
__device__ __forceinline__ void merge5(float a[KNN], const float b[KNN]) {
    const float c0 = fmaxf(a[0], b[0]);
    const float c1 = fmaxf(fmaxf(a[1], b[1]), fminf(a[0], b[0]));
    const float c2 = fmaxf(fmaxf(a[2], b[2]),
                           fmaxf(fminf(a[0], b[1]), fminf(a[1], b[0])));
    const float c3 = fmaxf(fmaxf(a[3], b[3]),
                           fmaxf(fminf(a[0], b[2]),
                                 fmaxf(fminf(a[1], b[1]), fminf(a[2], b[0]))));
    const float c4 = fmaxf(fmaxf(a[4], b[4]),
                           fmaxf(fmaxf(fminf(a[0], b[3]), fminf(a[1], b[2])),
                                 fmaxf(fminf(a[2], b[1]), fminf(a[3], b[0]))));
    a[0] = c0; a[1] = c1; a[2] = c2; a[3] = c3; a[4] = c4;
}

// ---------------------------------------------------------------------------
// Kernel 1: row-normalize x (fp32) -> xn (f16). One WAVE per row, 16B stores.
// ---------------------------------------------------------------------------
__global__ __launch_bounds__(256) void norm_kernel(const float* __restrict__ x,
                                                   _Float16* __restrict__ xnh,
                                                   float* __restrict__ out) {
    const int wv = threadIdx.x >> 6, lane = threadIdx.x & 63;
    const int row = blockIdx.x * 4 + wv;
    const float4* xr = (const float4*)(x + (size_t)row * DIM) + lane * 2;
    const float4 a = xr[0];
    const float4 b = xr[1];
    float s = a.x * a.x + a.y * a.y + a.z * a.z + a.w * a.w
            + b.x * b.x + b.y * b.y + b.z * b.z + b.w * b.w;
    #pragma unroll
    for (int off = 1; off < 64; off <<= 1) s += __shfl_xor(s, off, 64);
    const float inv = 1.0f / sqrtf(s);
    const f16x8 h = { (_Float16)(a.x * inv), (_Float16)(a.y * inv),
                      (_Float16)(a.z * inv), (_Float16)(a.w * inv),
                      (_Float16)(b.x * inv), (_Float16)(b.y * inv),
                      (_Float16)(b.z * inv), (_Float16)(b.w * inv) };
    *(f16x8*)(xnh + (size_t)row * DIM + lane * 8) = h;

    if (blockIdx.x == 0 && threadIdx.x == 0) *out = 0.f;
}

// ---------------------------------------------------------------------------
// Kernel 2: TRIANGULAR Gram-tile GEMM + per-(row, 64-col-tile) top-3.
// COMPACT grid: 2080 blocks, blockIdx -> (I,J) upper-triangular row-major
// (base(I) = I*(129-I)/2). BK=64: 8 staging steps, each 2 MFMA k-chunks ->
// half the barrier/drain events of BK=32. Row-side harvest -> M3[rows of I]
// [tiles of J]; col-side (dot symmetry) -> M3[rows of J][tiles of I].
// ---------------------------------------------------------------------------
__global__ __launch_bounds__(256) void dots_top3_kernel(const _Float16* __restrict__ xnh,
                                                        float* __restrict__ M3) {
    // blockIdx -> (I,J)
    const int t = blockIdx.x;
    int I = (int)((129.0f - sqrtf(16641.0f - 8.0f * (float)t)) * 0.5f);
    I = (I < 0) ? 0 : ((I > 63) ? 63 : I);
    while (I < 63 && (I + 1) * (128 - I) / 2 <= t) ++I;   // base(I+1) <= t
    while (I > 0 && I * (129 - I) / 2 > t) --I;           // base(I)   >  t
    const int J = I + (t - I * (129 - I) / 2);

    __shared__ __align__(16) _Float16 As[BM * BK];   // 16 KB
    __shared__ __align__(16) _Float16 Bs[BN * BK];   // 16 KB

    const int tid    = threadIdx.x;
    const int lane   = tid & 63;
    const int wv     = tid >> 6;
    const int wm     = wv >> 1;          // wave row half (0..1)
    const int wn     = wv & 1;           // wave col half (0..1)
    const int m_lane = lane & 15;        // MFMA: m (A) / n (B) / col (C)
    const int quad   = lane >> 4;        // MFMA: k-chunk (A,B) / row-group (C)

    const int i0 = I * BM;
    const int j0 = J * BN;
    const int rowlocal = (m_lane >> 2) * 16 + quad * 4 + (m_lane & 3);
    const int myrow    = i0 + wm * 64 + rowlocal;

    f32x4 acc[4][4];
    #pragma unroll
    for (int m = 0; m < 4; ++m)
        #pragma unroll
        for (int n = 0; n < 4; ++n)
            acc[m][n] = (f32x4){0.f, 0.f, 0.f, 0.f};

    for (int ks = 0; ks < DIM / BK; ++ks) {
        const int k0 = ks * BK;
        // stage A,B 128x64 tiles: 1024 x 16B slots each, 4 per thread each.
        // slot s: row = s>>3, chunk kk = s&7 (8 x 8-halfs per 64-wide row)
        #pragma unroll
        for (int q = 0; q < 4; ++q) {
            const int s  = tid + q * 256;
            const int r  = s >> 3;
            const int kk = s & 7;
            gload16(xnh + (size_t)(i0 + r) * DIM + k0 + kk * 8, As + s * 8);
            gload16(xnh + (size_t)(j0 + r) * DIM + k0 + kk * 8, Bs + s * 8);
        }
        __syncthreads();

        #pragma unroll
        for (int kc = 0; kc < 2; ++kc) {
            f16x8 af[4], bf[4];
            #pragma unroll
            for (int m = 0; m < 4; ++m)
                af[m] = *(const f16x8*)(As + (wm * 64 + m * 16 + m_lane) * BK
                                        + kc * 32 + quad * 8);
            #pragma unroll
            for (int n = 0; n < 4; ++n)
                bf[n] = *(const f16x8*)(Bs + (wn * 64 + n * 16 + m_lane) * BK
                                        + kc * 32 + quad * 8);
            #pragma unroll
            for (int m = 0; m < 4; ++m)
                #pragma unroll
                for (int n = 0; n < 4; ++n)
                    acc[m][n] = __builtin_amdgcn_mfma_f32_16x16x32_f16(af[m], bf[n], acc[m][n], 0, 0, 0);
        }
        __syncthreads();
    }

    // diagonal mask: self-dot only when I==J && wm==wn && m==n.
    const bool diag = (I == J) && (wm == wn);
    #pragma unroll
    for (int m = 0; m < 4; ++m)
        #pragma unroll
        for (int i = 0; i < 4; ++i)
            acc[m][m][i] = (diag && (quad * 4 + i) == m_lane) ? -2.f : acc[m][m][i];

    // ---- row-side: per (m,i), top-3 of this row's 64 cols (butterfly) ----
    float g1 = -2.f, g2 = -2.f, g3 = -2.f;
    #pragma unroll
    for (int m = 0; m < 4; ++m) {
        #pragma unroll
        for (int i = 0; i < 4; ++i) {
            float v0 = acc[m][0][i], v1 = acc[m][1][i];
            float v2 = acc[m][2][i], v3 = acc[m][3][i];
            cmpswap(v0, v1); cmpswap(v2, v3);
            cmpswap(v0, v2); cmpswap(v1, v3);
            cmpswap(v1, v2);                     // v0>=v1>=v2 (>=v3, dropped)
            float a1 = v0, a2 = v1, a3 = v2;
            #pragma unroll
            for (int d = 1; d < 16; d <<= 1) {
                const float b1 = __shfl_xor(a1, d, 64);
                const float b2 = __shfl_xor(a2, d, 64);
                const float b3 = __shfl_xor(a3, d, 64);
                const float n1 = fmaxf(a1, b1);
                const float n2 = fmaxf(fminf(a1, b1), fmaxf(a2, b2));
                const float n3 = fmaxf(fmaxf(a3, b3),
                                       fmaxf(fminf(a1, b2), fminf(a2, b1)));
                a1 = n1; a2 = n2; a3 = n3;
            }
            const bool own = (m_lane == m * 4 + i);
            g1 = own ? a1 : g1; g2 = own ? a2 : g2; g3 = own ? a3 : g3;
        }
    }
    {
        float* p = M3 + ((size_t)myrow * NT64 + (J * 2 + wn)) * 3;
        p[0] = g1; p[1] = g2; p[2] = g3;
    }

    // ---- col-side (I != J): per n, top-3 of this col's 64 rows ----
    if (I != J) {
        #pragma unroll
        for (int n = 0; n < 4; ++n) {
            float c1 = -2.f, c2 = -2.f, c3 = -2.f;
            #pragma unroll
            for (int m = 0; m < 4; ++m)
                #pragma unroll
                for (int i = 0; i < 4; ++i) {
                    const float v  = acc[m][n][i];
                    const float u1 = fminf(c1, v);
                    c1 = fmaxf(c1, v);
                    const float u2 = fminf(c2, u1);
                    c2 = fmaxf(c2, u1);
                    c3 = fmaxf(c3, u2);
                }
            #pragma unroll
            for (int d = 16; d < 64; d <<= 1) {
                const float b1 = __shfl_xor(c1, d, 64);
                const float b2 = __shfl_xor(c2, d, 64);
                const float b3 = __shfl_xor(c3, d, 64);
                const float n2 = fmaxf(fminf(c1, b1), fmaxf(c2, b2));
                const float n3 = fmaxf(fmaxf(c3, b3),
                                       fmaxf(fminf(c1, b2), fminf(c2, b1)));
                c1 = fmaxf(c1, b1); c2 = n2; c3 = n3;
            }
            if (quad == 0) {
                const int col = j0 + wn * 64 + n * 16 + m_lane;
                float* p = M3 + ((size_t)col * NT64 + (I * 2 + wm)) * 3;
                p[0] = c1; p[1] = c2; p[2] = c3;
            }
        }
    }
}

// ---------------------------------------------------------------------------
// Kernel 3: exact top-5 per row from the 128 stored triples + loss.
// One wave per row. Pool ⊆ full set ⇒ pool's t[4] ≤ true 5th-best; a tile can
// hide a missed value only if its stored 3rd ≥ t[4] — exactly recompute those.
// ---------------------------------------------------------------------------
__global__ __launch_bounds__(256) void select_loss_kernel(const _Float16* __restrict__ xnh,
                                                          const float* __restrict__ M3,
                                                          float* __restrict__ out) {
    const int wv = threadIdx.x >> 6, lane = threadIdx.x & 63;
    const int row = blockIdx.x * 4 + wv;
    const float* p = M3 + (size_t)row * NT64 * 3 + lane * 6;
    float a[3], b[3];
    a[0] = p[0]; a[1] = p[1]; a[2] = p[2];
    b[0] = p[3]; b[1] = p[4]; b[2] = p[5];

    float t[KNN];
    {
        float c[KNN] = { a[0], a[1], a[2], -2.f, -2.f };
        const float bb[KNN] = { b[0], b[1], b[2], -2.f, -2.f };
        merge5(c, bb);
        #pragma unroll
        for (int d = 1; d < 64; d <<= 1) {
            float o[KNN];
            #pragma unroll
            for (int k = 0; k < KNN; ++k) o[k] = __shfl_xor(c[k], d, 64);
            merge5(c, o);
        }
        #pragma unroll
        for (int k = 0; k < KNN; ++k) t[k] = c[k];
    }

    const unsigned long long ba  = __ballot(a[2] >= t[4]);
    const unsigned long long bb_ = __ballot(b[2] >= t[4]);
    if (ba | bb_) {
        const bool fA = (ba >> lane) & 1ull, fB = (bb_ >> lane) & 1ull;
        float c[KNN] = { fA ? -2.f : a[0], fA ? -2.f : a[1],
                         fA ? -2.f : a[2], -2.f, -2.f };
        const float b5[KNN] = { fB ? -2.f : b[0], fB ? -2.f : b[1],
                                fB ? -2.f : b[2], -2.f, -2.f };
        merge5(c, b5);
        #pragma unroll
        for (int d = 1; d < 64; d <<= 1) {
            float o[KNN];
            #pragma unroll
            for (int k = 0; k < KNN; ++k) o[k] = __shfl_xor(c[k], d, 64);
            merge5(c, o);
        }
        #pragma unroll
        for (int k = 0; k < KNN; ++k) t[k] = c[k];

        unsigned long long fl[2] = { ba, bb_ };
        #pragma unroll
        for (int h = 0; h < 2; ++h) {
            unsigned long long mm = fl[h];
            while (mm) {
                const int l = __ffsll((long long)mm) - 1;
                mm &= mm - 1;
                const int col = (2 * l + h) * 64 + lane;
                const _Float16* rp = xnh + (size_t)row * DIM;
                const _Float16* cp = xnh + (size_t)col * DIM;
                float d = 0.f;
                for (int k8 = 0; k8 < DIM / 8; ++k8) {
                    const f16x8 rv = *(const f16x8*)(rp + k8 * 8);
                    const f16x8 cv = *(const f16x8*)(cp + k8 * 8);
                    #pragma unroll
                    for (int e = 0; e < 8; ++e)
                        d += (float)rv[e] * (float)cv[e];
                }
                if (col == row) d = -2.f;
                float c2[KNN] = { d, -2.f, -2.f, -2.f, -2.f };
                #pragma unroll
                for (int dd = 1; dd < 64; dd <<= 1) {
                    float o[KNN];
                    #pragma unroll
                    for (int k = 0; k < KNN; ++k) o[k] = __shfl_xor(c2[k], dd, 64);
                    merge5(c2, o);
                }
                merge5(t, c2);
            }
        }
    }

    // loss: unit vectors -> dist_k = sqrt(2 - 2*dot_k)
    float s = 0.f;
    #pragma unroll
    for (int k = 0; k < KNN; ++k) s += sqrtf(fmaxf(2.f - 2.f * t[k], 0.f));
    const float val = logf(s * (1.f / KNN) + EPSV);

    __shared__ float red[4];
    if (lane == 0) red[wv] = val;
    __syncthreads();
    if (threadIdx.x == 0) {
        const float blocksum = red[0] + red[1] + red[2] + red[3];
        atomicAdd(out, -blocksum / (float)NROWS);
    }
}

// ---------------------------------------------------------------------------
extern "C" void kernel_launch(void* const* d_in, const int* in_sizes, int n_in,
                              void* d_out, int out_size, void* d_ws, size_t ws_size,
                              hipStream_t stream) {
    const float* x = (const float*)d_in[0];
    float* out = (float*)d_out;
    char* ws = (char*)d_ws;

    _Float16* xnh = (_Float16*)ws;                                     // 8 MB
    float* M3 = (float*)(ws + (size_t)NROWS * DIM * sizeof(_Float16)); // 12.6 MB

    norm_kernel<<<NROWS / 4, 256, 0, stream>>>(x, xnh, out);
    dots_top3_kernel<<<NTILES, 256, 0, stream>>>(xnh, M3);
    select_loss_kernel<<<NROWS / 4, 256, 0, stream>>>(xnh, M3, out);
}